// Round 1
// baseline (474.138 us; speedup 1.0000x reference)
//
#include <hip/hip_runtime.h>
#include <stdint.h>

// attention_block: B=8, S=2048, H=1024, fp32 in/out, bf16 internal GEMMs.
// Pipeline: gate(1xH GEMV) -> qW->bf16 -> LN(row) -> qr GEMM -> vr transpose
//        -> scores GEMM (+per-block max/sumexp) -> global reduce -> exp pass
//        -> PV GEMM (+1/Z, +xqn residual)

#define DEVI __device__ __forceinline__

typedef __bf16 bf16x8 __attribute__((ext_vector_type(8)));
typedef float  f32x4  __attribute__((ext_vector_type(4)));

typedef __attribute__((address_space(3))) uint32_t lds_u32_t;
typedef __attribute__((address_space(1))) uint32_t glb_u32_t;

DEVI uint16_t f2bf(float f) {
  union { float f; uint32_t u; } v; v.f = f;
  uint32_t r = (v.u + 0x7fffu + ((v.u >> 16) & 1u)) >> 16;  // RNE
  return (uint16_t)r;
}
DEVI float bf2f(uint16_t b) {
  union { uint32_t u; float f; } v; v.u = ((uint32_t)b) << 16;
  return v.f;
}
DEVI float sigm(float x) { return 1.0f / (1.0f + __expf(-x)); }

DEVI void gl_lds16(const void* g, const void* lds_base) {
  // async global->LDS, 16B/lane; LDS dest = wave-uniform base + lane*16
  __builtin_amdgcn_global_load_lds((glb_u32_t*)(uintptr_t)g,
                                   (lds_u32_t*)(uint32_t)(uintptr_t)lds_base,
                                   16, 0, 0);
}

// ---------------- core NT GEMM tile: C[128x128] += A[128xK] * B[128xK]^T ----
// A rows = M dim, B rows = N dim, both K-contiguous (bf16). 256 threads.
DEVI void gemm_tile(const uint16_t* __restrict__ A, int lda,
                    const uint16_t* __restrict__ B, int ldb,
                    int K, uint16_t* sA, uint16_t* sB, f32x4 acc[4][4])
{
  const int tid  = threadIdx.x;
  const int lane = tid & 63;
  const int w    = tid >> 6;
  const int wr   = (w >> 1) * 64;       // wave row offset in tile
  const int wc   = (w & 1) * 64;        // wave col offset in tile
  const int r0   = tid >> 2;            // staging row 0..63
  const int c0   = (tid & 3) * 8;       // staging col 0,8,16,24
  const int m16  = lane & 15;
  const int q8   = (lane >> 4) * 8;

  for (int kt = 0; kt < K; kt += 32) {
    __syncthreads();
#pragma unroll
    for (int p = 0; p < 2; p++) {
      gl_lds16(A + (size_t)(p * 64 + r0) * lda + (kt + c0), sA + (p * 256 + w * 64) * 8);
      gl_lds16(B + (size_t)(p * 64 + r0) * ldb + (kt + c0), sB + (p * 256 + w * 64) * 8);
    }
    __syncthreads();
    bf16x8 af[4], bfv[4];
#pragma unroll
    for (int i = 0; i < 4; i++) {
      af[i]  = *(const bf16x8*)(sA + (wr + i * 16 + m16) * 32 + q8);
      bfv[i] = *(const bf16x8*)(sB + (wc + i * 16 + m16) * 32 + q8);
    }
#pragma unroll
    for (int mi = 0; mi < 4; mi++)
#pragma unroll
      for (int ni = 0; ni < 4; ni++)
        acc[mi][ni] = __builtin_amdgcn_mfma_f32_16x16x32_bf16(af[mi], bfv[ni], acc[mi][ni], 0, 0, 0);
  }
}

// ---------------- gate: gate[j] = sig(vp.v1W[j]+v1b[j]) * tanh(vp.v2W[j]+v2b[j])
__global__ void gate_kernel(const float* __restrict__ v_prime,
                            const float* __restrict__ v1W, const float* __restrict__ v1b,
                            const float* __restrict__ v2W, const float* __restrict__ v2b,
                            float* __restrict__ gate)
{
  const int tid = threadIdx.x, lane = tid & 63, w = tid >> 6;
  const int j = blockIdx.x * 4 + w;
  float d1 = 0.f, d2 = 0.f;
  for (int it = 0; it < 16; it++) {
    int i = it * 64 + lane;
    float vp = sigm(v_prime[i]);
    d1 += vp * v1W[(size_t)j * 1024 + i];
    d2 += vp * v2W[(size_t)j * 1024 + i];
  }
  for (int off = 32; off; off >>= 1) { d1 += __shfl_xor(d1, off); d2 += __shfl_xor(d2, off); }
  if (lane == 0) gate[j] = sigm(d1 + v1b[j]) * tanhf(d2 + v2b[j]);
}

// ---------------- fp32 -> bf16 convert (qW) ----------------
__global__ void cvt_kernel(const float* __restrict__ src, uint16_t* __restrict__ dst)
{
  size_t i = ((size_t)blockIdx.x * 256 + threadIdx.x) * 4;
  float4 v = *(const float4*)(src + i);
  ushort4 o = make_ushort4(f2bf(v.x), f2bf(v.y), f2bf(v.z), f2bf(v.w));
  *(ushort4*)(dst + i) = o;
}

// ---------------- LayerNorm row kernel ----------------
__global__ __launch_bounds__(256) void ln_kernel(
    const float* __restrict__ x,
    const float* __restrict__ qn_w, const float* __restrict__ qn_b,
    const float* __restrict__ kvn_w, const float* __restrict__ kvn_b,
    const float* __restrict__ k_prime, const float* __restrict__ gate,
    float* __restrict__ xqn_f32, uint16_t* __restrict__ xqn_bf,
    uint16_t* __restrict__ kr, uint16_t* __restrict__ vr)
{
  const int row = blockIdx.x, tid = threadIdx.x, lane = tid & 63, w = tid >> 6;
  float4 v = ((const float4*)(x + (size_t)row * 1024))[tid];
  float s  = v.x + v.y + v.z + v.w;
  float sq = v.x * v.x + v.y * v.y + v.z * v.z + v.w * v.w;
  for (int off = 32; off; off >>= 1) { s += __shfl_xor(s, off); sq += __shfl_xor(sq, off); }
  __shared__ float rs[4], rq[4];
  if (lane == 0) { rs[w] = s; rq[w] = sq; }
  __syncthreads();
  s  = rs[0] + rs[1] + rs[2] + rs[3];
  sq = rq[0] + rq[1] + rq[2] + rq[3];
  const float mean = s * (1.f / 1024.f);
  const float var  = sq * (1.f / 1024.f) - mean * mean;
  const float rstd = rsqrtf(var + 1e-5f);

  float4 qw = ((const float4*)qn_w)[tid],  qb4 = ((const float4*)qn_b)[tid];
  float4 kw = ((const float4*)kvn_w)[tid], kb4 = ((const float4*)kvn_b)[tid];
  float4 kp = ((const float4*)k_prime)[tid], g = ((const float4*)gate)[tid];

  float xn0 = (v.x - mean) * rstd, xn1 = (v.y - mean) * rstd;
  float xn2 = (v.z - mean) * rstd, xn3 = (v.w - mean) * rstd;
  float xq0 = xn0 * qw.x + qb4.x, xq1 = xn1 * qw.y + qb4.y;
  float xq2 = xn2 * qw.z + qb4.z, xq3 = xn3 * qw.w + qb4.w;
  float xk0 = xn0 * kw.x + kb4.x, xk1 = xn1 * kw.y + kb4.y;
  float xk2 = xn2 * kw.z + kb4.z, xk3 = xn3 * kw.w + kb4.w;

  size_t o4 = (size_t)row * 256 + tid;
  ((float4*)xqn_f32)[o4] = make_float4(xq0, xq1, xq2, xq3);
  ((ushort4*)xqn_bf)[o4] = make_ushort4(f2bf(xq0), f2bf(xq1), f2bf(xq2), f2bf(xq3));
  ((ushort4*)kr)[o4] = make_ushort4(f2bf(xk0 * sigm(kp.x)), f2bf(xk1 * sigm(kp.y)),
                                    f2bf(xk2 * sigm(kp.z)), f2bf(xk3 * sigm(kp.w)));
  ((ushort4*)vr)[o4] = make_ushort4(f2bf(xk0 * g.x), f2bf(xk1 * g.y),
                                    f2bf(xk2 * g.z), f2bf(xk3 * g.w));
}

// ---------------- qr GEMM: qr = (xqn @ qW^T + qb) * sig(q_prime) ----------
__global__ __launch_bounds__(256) void qr_gemm_kernel(
    const uint16_t* __restrict__ xqn_bf, const uint16_t* __restrict__ qWbf,
    const float* __restrict__ qb, const float* __restrict__ q_prime,
    uint16_t* __restrict__ qr)
{
  __shared__ uint16_t sA[128 * 32], sB[128 * 32];
  f32x4 acc[4][4];
#pragma unroll
  for (int i = 0; i < 4; i++)
#pragma unroll
    for (int j = 0; j < 4; j++) acc[i][j] = (f32x4)0.0f;

  const int rowBase = blockIdx.y * 128, colBase = blockIdx.x * 128;
  gemm_tile(xqn_bf + (size_t)rowBase * 1024, 1024,
            qWbf + (size_t)colBase * 1024, 1024, 1024, sA, sB, acc);

  const int lane = threadIdx.x & 63, w = threadIdx.x >> 6;
  const int wr = (w >> 1) * 64, wc = (w & 1) * 64;
#pragma unroll
  for (int ni = 0; ni < 4; ni++) {
    int gc = colBase + wc + ni * 16 + (lane & 15);
    float scale = sigm(q_prime[gc]);
    float bias = qb[gc];
#pragma unroll
    for (int mi = 0; mi < 4; mi++)
#pragma unroll
      for (int r = 0; r < 4; r++) {
        int gr = rowBase + wr + mi * 16 + (lane >> 4) * 4 + r;
        qr[(size_t)gr * 1024 + gc] = f2bf((acc[mi][ni][r] + bias) * scale);
      }
  }
}

// ---------------- transpose vr [b,t,h] -> vrt [b,h,t] (bf16) --------------
__global__ void transpose_kernel(const uint16_t* __restrict__ vr, uint16_t* __restrict__ vrt)
{
  __shared__ uint16_t t[64 * 72];
  const int b = blockIdx.z;
  const int t0 = blockIdx.x * 64, h0 = blockIdx.y * 64;
  const uint16_t* src = vr + (size_t)b * 2048 * 1024;
#pragma unroll
  for (int p = 0; p < 2; p++) {
    int flat = p * 256 + threadIdx.x;
    int r = flat >> 3, c = (flat & 7) * 8;
    *(uint4*)(&t[r * 72 + c]) = *(const uint4*)(src + (size_t)(t0 + r) * 1024 + h0 + c);
  }
  __syncthreads();
  uint16_t* dst = vrt + (size_t)b * 1024 * 2048;
#pragma unroll
  for (int p = 0; p < 2; p++) {
    int flat = p * 256 + threadIdx.x;
    int oh = flat >> 3, oc = (flat & 7) * 8;
    union { uint16_t e[8]; uint4 v; } u;
#pragma unroll
    for (int j = 0; j < 8; j++) u.e[j] = t[(oc + j) * 72 + oh];
    *(uint4*)(dst + (size_t)(h0 + oh) * 2048 + t0 + oc) = u.v;
  }
}

// ---------------- scores GEMM (+ per-block max / sumexp) ------------------
__global__ __launch_bounds__(256) void scores_kernel(
    const uint16_t* __restrict__ qr, const uint16_t* __restrict__ kr,
    uint16_t* __restrict__ scores, float* __restrict__ blockM, float* __restrict__ blockZ)
{
  __shared__ uint16_t sA[128 * 32], sB[128 * 32];
  __shared__ float redm[4], redz[4];
  const int b = blockIdx.z;
  f32x4 acc[4][4];
#pragma unroll
  for (int i = 0; i < 4; i++)
#pragma unroll
    for (int j = 0; j < 4; j++) acc[i][j] = (f32x4)0.0f;

  const uint16_t* A = qr + (size_t)b * 2048 * 1024 + (size_t)blockIdx.y * 128 * 1024;
  const uint16_t* B = kr + (size_t)b * 2048 * 1024 + (size_t)blockIdx.x * 128 * 1024;
  gemm_tile(A, 1024, B, 1024, 1024, sA, sB, acc);

  const int lane = threadIdx.x & 63, w = threadIdx.x >> 6;
  const int wr = (w >> 1) * 64, wc = (w & 1) * 64;
  uint16_t* S = scores + ((size_t)b << 22);
  const int rb = blockIdx.y * 128 + wr, cb = blockIdx.x * 128 + wc;

  float mt = -1e30f;
#pragma unroll
  for (int mi = 0; mi < 4; mi++)
#pragma unroll
    for (int ni = 0; ni < 4; ni++)
#pragma unroll
      for (int r = 0; r < 4; r++) {
        float s = acc[mi][ni][r] * 0.03125f;  // / sqrt(1024)
        acc[mi][ni][r] = s;
        mt = fmaxf(mt, s);
        S[(size_t)(rb + mi * 16 + (lane >> 4) * 4 + r) * 2048 + (cb + ni * 16 + (lane & 15))] = f2bf(s);
      }
  for (int off = 32; off; off >>= 1) mt = fmaxf(mt, __shfl_xor(mt, off));
  if (lane == 0) redm[w] = mt;
  __syncthreads();
  const float mb = fmaxf(fmaxf(redm[0], redm[1]), fmaxf(redm[2], redm[3]));
  float zt = 0.f;
#pragma unroll
  for (int mi = 0; mi < 4; mi++)
#pragma unroll
    for (int ni = 0; ni < 4; ni++)
#pragma unroll
      for (int r = 0; r < 4; r++) zt += __expf(acc[mi][ni][r] - mb);
  for (int off = 32; off; off >>= 1) zt += __shfl_xor(zt, off);
  if (lane == 0) redz[w] = zt;
  __syncthreads();
  if (threadIdx.x == 0) {
    int bid = (blockIdx.z * gridDim.y + blockIdx.y) * gridDim.x + blockIdx.x;
    blockM[bid] = mb;
    blockZ[bid] = redz[0] + redz[1] + redz[2] + redz[3];
  }
}

// ---------------- global softmax reduce: per-batch M, Z -------------------
__global__ void softmax_reduce_kernel(const float* __restrict__ blockM,
                                      const float* __restrict__ blockZ,
                                      float* __restrict__ MZ)
{
  __shared__ float rm[4], rz[4];
  const int tid = threadIdx.x, lane = tid & 63, w = tid >> 6;
  for (int b = 0; b < 8; b++) {
    float mloc = blockM[b * 256 + tid];
    float m = mloc;
    for (int off = 32; off; off >>= 1) m = fmaxf(m, __shfl_xor(m, off));
    if (lane == 0) rm[w] = m;
    __syncthreads();
    float Mb = fmaxf(fmaxf(rm[0], rm[1]), fmaxf(rm[2], rm[3]));
    float z = blockZ[b * 256 + tid] * __expf(mloc - Mb);
    for (int off = 32; off; off >>= 1) z += __shfl_xor(z, off);
    if (lane == 0) rz[w] = z;
    __syncthreads();
    if (tid == 0) { MZ[b] = Mb; MZ[8 + b] = rz[0] + rz[1] + rz[2] + rz[3]; }
    __syncthreads();
  }
}

// ---------------- elementwise exp: P = exp(s - M[b]) (in place) -----------
__global__ void exp_kernel(uint16_t* __restrict__ scores, const float* __restrict__ MZ)
{
  const int b = blockIdx.y;
  const float Mb = MZ[b];
  size_t idx = ((size_t)b << 22) + ((size_t)blockIdx.x * 256 + threadIdx.x) * 8;
  union { uint4 v; uint16_t e[8]; } u;
  u.v = *(const uint4*)(scores + idx);
#pragma unroll
  for (int j = 0; j < 8; j++) u.e[j] = f2bf(__expf(bf2f(u.e[j]) - Mb));
  *(uint4*)(scores + idx) = u.v;
}

// ---------------- PV GEMM: out = P @ vrt^T / Z + xqn ----------------------
__global__ __launch_bounds__(256) void pv_gemm_kernel(
    const uint16_t* __restrict__ P, const uint16_t* __restrict__ vrt,
    const float* __restrict__ MZ, const float* __restrict__ xqn,
    float* __restrict__ out)
{
  __shared__ uint16_t sA[128 * 32], sB[128 * 32];
  const int b = blockIdx.z;
  f32x4 acc[4][4];
#pragma unroll
  for (int i = 0; i < 4; i++)
#pragma unroll
    for (int j = 0; j < 4; j++) acc[i][j] = (f32x4)0.0f;

  const uint16_t* A = P + ((size_t)b << 22) + (size_t)blockIdx.y * 128 * 2048;
  const uint16_t* B = vrt + (size_t)b * 1024 * 2048 + (size_t)blockIdx.x * 128 * 2048;
  gemm_tile(A, 2048, B, 2048, 2048, sA, sB, acc);

  const float invZ = 1.0f / MZ[8 + b];
  const int lane = threadIdx.x & 63, w = threadIdx.x >> 6;
  const int wr = (w >> 1) * 64, wc = (w & 1) * 64;
  const int rb = blockIdx.y * 128 + wr, cb = blockIdx.x * 128 + wc;
#pragma unroll
  for (int mi = 0; mi < 4; mi++)
#pragma unroll
    for (int ni = 0; ni < 4; ni++)
#pragma unroll
      for (int r = 0; r < 4; r++) {
        int gr = rb + mi * 16 + (lane >> 4) * 4 + r;
        int gc = cb + ni * 16 + (lane & 15);
        size_t o = ((size_t)b * 2048 + gr) * 1024 + gc;
        out[o] = acc[mi][ni][r] * invZ + xqn[o];
      }
}

extern "C" void kernel_launch(void* const* d_in, const int* in_sizes, int n_in,
                              void* d_out, int out_size, void* d_ws, size_t ws_size,
                              hipStream_t stream) {
  const float* x       = (const float*)d_in[0];
  const float* qn_w    = (const float*)d_in[1];
  const float* qn_b    = (const float*)d_in[2];
  const float* kvn_w   = (const float*)d_in[3];
  const float* kvn_b   = (const float*)d_in[4];
  const float* q_prime = (const float*)d_in[5];
  const float* k_prime = (const float*)d_in[6];
  const float* v_prime = (const float*)d_in[7];
  const float* qW      = (const float*)d_in[8];
  const float* qb      = (const float*)d_in[9];
  const float* v1W     = (const float*)d_in[10];
  const float* v1b     = (const float*)d_in[11];
  const float* v2W     = (const float*)d_in[12];
  const float* v2b     = (const float*)d_in[13];
  float* out = (float*)d_out;

  const size_t BS = 16384;           // B*S rows
  const size_t H  = 1024;
  char* ws = (char*)d_ws;
  size_t off = 0;
  auto alloc = [&](size_t bytes) -> char* {
    char* p = ws + off;
    off = (off + bytes + 255) & ~(size_t)255;
    return p;
  };
  float*    gate    = (float*)alloc(H * 4);
  float*    MZ      = (float*)alloc(16 * 4);
  float*    blockM  = (float*)alloc(2048 * 4);
  float*    blockZ  = (float*)alloc(2048 * 4);
  uint16_t* qWbf    = (uint16_t*)alloc(H * H * 2);
  float*    xqn_f32 = (float*)alloc(BS * H * 4);
  // region C: [xqn_bf | vr] early, reused as scores (64 MB) after both are dead
  char*     regionC = alloc(BS * H * 2 * 2);
  uint16_t* xqn_bf  = (uint16_t*)regionC;
  uint16_t* vr      = (uint16_t*)(regionC + BS * H * 2);
  uint16_t* scores  = (uint16_t*)regionC;          // aliases xqn_bf+vr (dead by then)
  uint16_t* kr      = (uint16_t*)alloc(BS * H * 2);
  uint16_t* vrt     = (uint16_t*)alloc(BS * H * 2);
  uint16_t* qr      = (uint16_t*)alloc(BS * H * 2);

  gate_kernel<<<256, 256, 0, stream>>>(v_prime, v1W, v1b, v2W, v2b, gate);
  cvt_kernel<<<1024, 256, 0, stream>>>(qW, qWbf);
  ln_kernel<<<16384, 256, 0, stream>>>(x, qn_w, qn_b, kvn_w, kvn_b, k_prime, gate,
                                       xqn_f32, xqn_bf, kr, vr);
  qr_gemm_kernel<<<dim3(8, 128), 256, 0, stream>>>(xqn_bf, qWbf, qb, q_prime, qr);
  transpose_kernel<<<dim3(32, 16, 8), 256, 0, stream>>>(vr, vrt);
  // from here on, xqn_bf and vr are dead; scores may overwrite region C
  scores_kernel<<<dim3(16, 16, 8), 256, 0, stream>>>(qr, kr, scores, blockM, blockZ);
  softmax_reduce_kernel<<<1, 256, 0, stream>>>(blockM, blockZ, MZ);
  exp_kernel<<<dim3(2048, 8), 256, 0, stream>>>(scores, MZ);
  pv_gemm_kernel<<<dim3(8, 16, 8), 256, 0, stream>>>(scores, vrt, MZ, xqn_f32, out);
}